// Round 6
// baseline (4637.147 us; speedup 1.0000x reference)
//
#include <hip/hip_runtime.h>
#include <hip/hip_bf16.h>

// Problem sizes (fixed)
#define BB 32
#define TT 512
#define HH 1024
#define II 1024
#define G4H 4096
#define BH  (BB * HH)          // 32768

typedef __bf16 bf16x8_t __attribute__((ext_vector_type(8)));
typedef float f32x4_t __attribute__((ext_vector_type(4)));
typedef int i32x4_t __attribute__((ext_vector_type(4)));
typedef unsigned long long u64;

// ---------------------------------------------------------------------------
// Zero rotating h buffers + arrive flags. (ws re-poisoned 0xAA each call)
// grid: 256 x 256 covers 65536 = 2*BH
// ---------------------------------------------------------------------------
__global__ void init_bufs(__hip_bfloat16* __restrict__ h0buf,
                          __hip_bfloat16* __restrict__ h1buf,
                          unsigned* __restrict__ arr) {
    int i = blockIdx.x * 256 + threadIdx.x;
    h0buf[i] = __float2bfloat16(0.f);
    h1buf[i] = __float2bfloat16(0.f);
    if (i < 8192) arr[i] = 0u;
}

// ---------------------------------------------------------------------------
// Weight shuffle: fp32 [4096][1024] -> bf16 B-fragment order.
// dst bits: jj:3 | lane:6 | kb:4 | kh:1 | tau:1 | hg:7
//   n=lane&15, q=lane>>4
//   row = (2*tau + (n>>3))*1024 + hg*8 + (n&7)
//   col = kh*512 + kb*32 + q*8 + jj
// ---------------------------------------------------------------------------
__global__ void shuffle_w(const float* __restrict__ src, __hip_bfloat16* __restrict__ dst) {
    size_t i = (size_t)blockIdx.x * 256 + threadIdx.x;   // 0 .. 4M-1
    int jj   = (int)(i & 7);
    int lane = (int)((i >> 3) & 63);
    int kb   = (int)((i >> 9) & 15);
    int kh   = (int)((i >> 13) & 1);
    int tau  = (int)((i >> 14) & 1);
    int hg   = (int)(i >> 15);
    int n = lane & 15, q = lane >> 4;
    int row = (2 * tau + (n >> 3)) * 1024 + hg * 8 + (n & 7);
    int col = kh * 512 + kb * 32 + q * 8 + jj;
    dst[i] = __float2bfloat16(src[(size_t)row * II + col]);
}

// ---------------------------------------------------------------------------
// x [B][T][I] fp32 -> xb [T][B][I] bf16
// ---------------------------------------------------------------------------
__global__ void convert_x(const float* __restrict__ x, __hip_bfloat16* __restrict__ xb) {
    size_t i = (size_t)blockIdx.x * 256 + threadIdx.x;   // T*B*I
    int ii = (int)(i & 1023);
    int b  = (int)((i >> 10) & 31);
    int t  = (int)(i >> 15);
    xb[i] = __float2bfloat16(x[((size_t)b * TT + t) * II + ii]);
}

// ---------------------------------------------------------------------------
// Persistent fused 2-layer LSTM. 256 WGs (1/CU) x 512 threads (8 waves).
// WG wg: bh = wg>>7 (batch half), hg = wg&127 (8 h-dims -> 32 gate rows).
// wave: L = w>>2, p = (w>>1)&1, kh = w&1.
//   waves 0,1: L0 x-GEMM  -- precomputed during the PREVIOUS phase's barrier
//   waves 2,3: L0 h-GEMM  (A = h0(t-1), agent-scope u64 loads)
//   waves 4,5: L1 x-GEMM  (A = h0(t-1))        + barrier POLL duty
//   waves 6,7: L1 h-GEMM  (A = h1(t-2))        + wave6: out stores (deferred,
//              plain cached) / wave7: aggregated h stores + arrive flag
// Weights pinned in regs via empty-asm "+v" (32 x i32x4 per wave).
// Phase t = layer0@t + layer1@(t-1), skewed, 513 phases.
//
// Coherence: h producers -> LDS -> wave7 u64 cache-bypassing agent stores
// (4 dims/lane: 8 same-line writers at MALL instead of 32); wave7 drains its
// own vmcnt then stores the arrive flag (flag implies h visible). Consumers
// read h with agent-scope u64 atomic loads (no buffer_inv, L2 keeps xb hot).
// out is written with plain cached stores AFTER the flag: drains during the
// poll window; dispatch-end writeback makes it visible to the host.
// Barrier: all-to-all within the 128-WG bh-group (1 flag store, waves 4,5's
// 128 threads each poll one flag line).
// ---------------------------------------------------------------------------
__global__ __launch_bounds__(512, 2)
void lstm_persist(const __hip_bfloat16* __restrict__ xb,
                  const __hip_bfloat16* __restrict__ Wxs0, const __hip_bfloat16* __restrict__ Whs0,
                  const __hip_bfloat16* __restrict__ Wxs1, const __hip_bfloat16* __restrict__ Whs1,
                  const float* __restrict__ bih0, const float* __restrict__ bhh0,
                  const float* __restrict__ bih1, const float* __restrict__ bhh1,
                  __hip_bfloat16* __restrict__ h0buf,   // [2][BH] rotating
                  __hip_bfloat16* __restrict__ h1buf,   // [2][BH] rotating
                  float* __restrict__ out,              // [B][T][H]
                  unsigned* __restrict__ arr)           // [256][32] arrive flags
{
    const int wg = blockIdx.x, tid = threadIdx.x;
    const int bh = wg >> 7, hg = wg & 127;
    const int wave = tid >> 6, lane = tid & 63;
    const int L = wave >> 2, p = (wave >> 1) & 1, kh = wave & 1;
    const int n = lane & 15, q = lane >> 4;

    __shared__ float psum[2][2][2][16][37];       // [L][p][kh][batch][tau*16+n]
    __shared__ float res[2][128];                 // fp32 h0 hand-off for residual
    __shared__ alignas(8) __hip_bfloat16 hstage[2][128];  // pointwise -> wave7/wave6

    // ---- load B-fragments once, pin in registers ----
    const __hip_bfloat16* Wsel = L ? (p ? Whs1 : Wxs1) : (p ? Whs0 : Wxs0);
    const __bf16* wbp = (const __bf16*)Wsel;

    i32x4_t W0, W1, W2, W3, W4, W5, W6, W7, W8, W9, W10, W11, W12, W13, W14, W15,
            W16, W17, W18, W19, W20, W21, W22, W23, W24, W25, W26, W27, W28, W29, W30, W31;
#define LOADW(IDX, TAU, KB) \
    W##IDX = *(const i32x4_t*)(const void*)(wbp + ((((((size_t)hg * 2 + (TAU)) * 2 + kh) * 16) + (KB)) * 64 + lane) * 8)
    LOADW(0,0,0);  LOADW(1,0,1);  LOADW(2,0,2);  LOADW(3,0,3);
    LOADW(4,0,4);  LOADW(5,0,5);  LOADW(6,0,6);  LOADW(7,0,7);
    LOADW(8,0,8);  LOADW(9,0,9);  LOADW(10,0,10); LOADW(11,0,11);
    LOADW(12,0,12); LOADW(13,0,13); LOADW(14,0,14); LOADW(15,0,15);
    LOADW(16,1,0);  LOADW(17,1,1);  LOADW(18,1,2);  LOADW(19,1,3);
    LOADW(20,1,4);  LOADW(21,1,5);  LOADW(22,1,6);  LOADW(23,1,7);
    LOADW(24,1,8);  LOADW(25,1,9);  LOADW(26,1,10); LOADW(27,1,11);
    LOADW(28,1,12); LOADW(29,1,13); LOADW(30,1,14); LOADW(31,1,15);
#undef LOADW
    asm volatile("" : "+v"(W0), "+v"(W1), "+v"(W2), "+v"(W3),
                      "+v"(W4), "+v"(W5), "+v"(W6), "+v"(W7));
    asm volatile("" : "+v"(W8), "+v"(W9), "+v"(W10), "+v"(W11),
                      "+v"(W12), "+v"(W13), "+v"(W14), "+v"(W15));
    asm volatile("" : "+v"(W16), "+v"(W17), "+v"(W18), "+v"(W19),
                      "+v"(W20), "+v"(W21), "+v"(W22), "+v"(W23));
    asm volatile("" : "+v"(W24), "+v"(W25), "+v"(W26), "+v"(W27),
                      "+v"(W28), "+v"(W29), "+v"(W30), "+v"(W31));

    // ---- pointwise thread state (tid<256): biases in regs, c in a reg ----
    const int pw_L = tid >> 7, pw_idx = tid & 127, pw_b = (tid >> 3) & 15, pw_d = tid & 7;
    float bias_r[4] = {0.f, 0.f, 0.f, 0.f};
    float c_reg = 0.f;
    if (tid < 256) {
        const float* bi  = pw_L ? bih1 : bih0;
        const float* bh2 = pw_L ? bhh1 : bhh0;
#pragma unroll
        for (int g = 0; g < 4; ++g) {
            int row = g * 1024 + hg * 8 + pw_d;
            bias_r[g] = bi[row] + bh2[row];
        }
    }

    const int arow = bh * 16 + n;
    const unsigned* poll_line = &arr[(size_t)(bh * 128 + (tid & 127)) * 32];

#define MFMA16(AV, B8, ACC) __builtin_amdgcn_mfma_f32_16x16x32_bf16(AV, B8, ACC, 0, 0, 0)
#define MSTEP(AV, IA, IB) \
    acc0 = MFMA16(AV, __builtin_bit_cast(bf16x8_t, W##IA), acc0); \
    acc1 = MFMA16(AV, __builtin_bit_cast(bf16x8_t, W##IB), acc1)
#define ASTEP(KB, IA, IB) { \
    union { u64 qq[2]; bf16x8_t v; } u_; \
    u_.qq[0] = __hip_atomic_load(ab + (KB) * 8,     __ATOMIC_RELAXED, __HIP_MEMORY_SCOPE_AGENT); \
    u_.qq[1] = __hip_atomic_load(ab + (KB) * 8 + 1, __ATOMIC_RELAXED, __HIP_MEMORY_SCOPE_AGENT); \
    MSTEP(u_.v, IA, IB); }
#define XSTEP(KB, IA, IB) { \
    bf16x8_t av = *(const bf16x8_t*)(const void*)(a_base + (KB) * 32); \
    acc0 = MFMA16(av, __builtin_bit_cast(bf16x8_t, W##IA), acc0); \
    acc1 = MFMA16(av, __builtin_bit_cast(bf16x8_t, W##IB), acc1); }

    // ---- bootstrap: waves 0,1 precompute x-GEMM for t=0 ----
    f32x4_t axs0 = {0.f, 0.f, 0.f, 0.f}, axs1 = {0.f, 0.f, 0.f, 0.f};
    if (wave < 2) {
        f32x4_t acc0 = {0.f, 0.f, 0.f, 0.f}, acc1 = {0.f, 0.f, 0.f, 0.f};
        const __bf16* a_base = (const __bf16*)xb + arow * 1024 + kh * 512 + q * 8;
        XSTEP(0,0,16);  XSTEP(1,1,17);  XSTEP(2,2,18);  XSTEP(3,3,19);
        XSTEP(4,4,20);  XSTEP(5,5,21);  XSTEP(6,6,22);  XSTEP(7,7,23);
        XSTEP(8,8,24);  XSTEP(9,9,25);  XSTEP(10,10,26); XSTEP(11,11,27);
        XSTEP(12,12,28); XSTEP(13,13,29); XSTEP(14,14,30); XSTEP(15,15,31);
        axs0 = acc0; axs1 = acc1;
    }

    for (int t = 0; t <= TT; ++t) {
        // ========== stage 1: GEMMs ==========
        f32x4_t acc0, acc1;
        if (wave < 2) {
            acc0 = axs0; acc1 = axs1;     // precomputed during previous barrier window
        } else {
            const __hip_bfloat16* Abuf = (L == 1 && p == 1)
                ? (h1buf + (size_t)(t & 1) * BH)            // h1(t-2)
                : (h0buf + (size_t)((t + 1) & 1) * BH);     // h0(t-1)
            const u64* ab = (const u64*)(const void*)((const __bf16*)Abuf
                             + arow * 1024 + kh * 512 + q * 8);
            acc0 = (f32x4_t){0.f, 0.f, 0.f, 0.f};
            acc1 = (f32x4_t){0.f, 0.f, 0.f, 0.f};
            ASTEP(0,0,16);  ASTEP(1,1,17);  ASTEP(2,2,18);  ASTEP(3,3,19);
            ASTEP(4,4,20);  ASTEP(5,5,21);  ASTEP(6,6,22);  ASTEP(7,7,23);
            ASTEP(8,8,24);  ASTEP(9,9,25);  ASTEP(10,10,26); ASTEP(11,11,27);
            ASTEP(12,12,28); ASTEP(13,13,29); ASTEP(14,14,30); ASTEP(15,15,31);
        }
        // C/D: lane holds D[i = q*4+r][j = n]
#pragma unroll
        for (int r = 0; r < 4; ++r) {
            psum[L][p][kh][q * 4 + r][n] = acc0[r];
            psum[L][p][kh][q * 4 + r][16 + n] = acc1[r];
        }
        __syncthreads();

        // ========== stage 2: pointwise -> LDS ==========
        if (tid < 256) {
            const bool active = pw_L ? (t >= 1) : (t < TT);
            if (active) {
                float gv[4];
#pragma unroll
                for (int g = 0; g < 4; ++g) {
                    int col = (g >> 1) * 16 + (g & 1) * 8 + pw_d;
                    gv[g] = psum[pw_L][0][0][pw_b][col] + psum[pw_L][0][1][pw_b][col]
                          + psum[pw_L][1][0][pw_b][col] + psum[pw_L][1][1][pw_b][col]
                          + bias_r[g];
                }
                float si = 1.f / (1.f + __expf(-gv[0]));
                float sf = 1.f / (1.f + __expf(-gv[1]));
                float tg = 2.f / (1.f + __expf(-2.f * gv[2])) - 1.f;
                float so = 1.f / (1.f + __expf(-gv[3]));
                c_reg = sf * c_reg + si * tg;
                float hv = so * (2.f / (1.f + __expf(-2.f * c_reg)) - 1.f);
                hstage[pw_L][pw_idx] = __float2bfloat16(hv);
                if (pw_L == 0) res[t & 1][pw_idx] = hv;
            }
        }
        __syncthreads();   // hstage/res ready

        // ========== stage 3: barrier window (roles in parallel) ==========
        if (wave < 2) {
            // precompute x-GEMM for phase t+1 (x always available; overlaps barrier)
            const int tn = (t + 1 < TT) ? (t + 1) : (TT - 1);
            f32x4_t b0 = {0.f, 0.f, 0.f, 0.f}, b1 = {0.f, 0.f, 0.f, 0.f};
            {
                f32x4_t acc0 = b0, acc1 = b1;
                const __bf16* a_base = (const __bf16*)xb + (size_t)tn * BH
                                       + arow * 1024 + kh * 512 + q * 8;
                XSTEP(0,0,16);  XSTEP(1,1,17);  XSTEP(2,2,18);  XSTEP(3,3,19);
                XSTEP(4,4,20);  XSTEP(5,5,21);  XSTEP(6,6,22);  XSTEP(7,7,23);
                XSTEP(8,8,24);  XSTEP(9,9,25);  XSTEP(10,10,26); XSTEP(11,11,27);
                XSTEP(12,12,28); XSTEP(13,13,29); XSTEP(14,14,30); XSTEP(15,15,31);
                b0 = acc0; b1 = acc1;
            }
            axs0 = b0; axs1 = b1;
        } else if (wave == 7) {
            // aggregated cache-bypassing h stores: 4 dims per lane (u64)
            const int ly = lane >> 5, sub = lane & 31;
            const int b = sub >> 1, dq = sub & 1;
            const bool st = ly ? (t >= 1) : (t < TT);
            if (st) {
                u64 v = *(const u64*)(const void*)&hstage[ly][b * 8 + dq * 4];
                __hip_bfloat16* hb = ly ? h1buf : h0buf;
                const size_t par = ly ? (size_t)((t - 1) & 1) : (size_t)(t & 1);
                u64* dst = (u64*)(void*)(hb + par * BH
                            + (size_t)(bh * 16 + b) * 1024 + hg * 8 + dq * 4);
                __hip_atomic_store(dst, v, __ATOMIC_RELAXED, __HIP_MEMORY_SCOPE_AGENT);
            }
            asm volatile("s_waitcnt vmcnt(0)" ::: "memory");   // my h stores at IF
            if (lane == 0 && t < TT)
                __hip_atomic_store(&arr[(size_t)wg * 32], (unsigned)(t + 1),
                                   __ATOMIC_RELAXED, __HIP_MEMORY_SCOPE_AGENT);
        } else if (wave == 6) {
            // deferred residual out stores (plain cached; drain overlaps poll,
            // dispatch-end writeback publishes to host)
            if (t >= 1) {
                const int i0 = lane * 2;
                const int b = i0 >> 3, d = i0 & 7;
                const float* rp = res[(t + 1) & 1];
                float2 o;
                o.x = rp[i0]     + __bfloat162float(hstage[1][i0]);
                o.y = rp[i0 + 1] + __bfloat162float(hstage[1][i0 + 1]);
                *(float2*)(void*)&out[(size_t)(bh * 16 + b) * TT * HH
                                      + (size_t)(t - 1) * HH + hg * 8 + d] = o;
            }
        } else if (wave == 4 || wave == 5) {
            // poll duty: 128 threads, one flag line each
            if (t < TT) {
                const unsigned tgt = (unsigned)(t + 1);
                while (__hip_atomic_load(poll_line, __ATOMIC_RELAXED,
                                         __HIP_MEMORY_SCOPE_AGENT) < tgt)
                    __builtin_amdgcn_s_sleep(1);
            }
        }
        __syncthreads();   // barrier passed; next phase's h loads are safe
    }
#undef MFMA16
#undef MSTEP
#undef ASTEP
#undef XSTEP
}

// ---------------------------------------------------------------------------
// Host side
// ---------------------------------------------------------------------------
extern "C" void kernel_launch(void* const* d_in, const int* in_sizes, int n_in,
                              void* d_out, int out_size, void* d_ws, size_t ws_size,
                              hipStream_t stream) {
    const float* x    = (const float*)d_in[0];
    const float* Wih0 = (const float*)d_in[1];
    const float* Whh0 = (const float*)d_in[2];
    const float* bih0 = (const float*)d_in[3];
    const float* bhh0 = (const float*)d_in[4];
    const float* Wih1 = (const float*)d_in[5];
    const float* Whh1 = (const float*)d_in[6];
    const float* bih1 = (const float*)d_in[7];
    const float* bhh1 = (const float*)d_in[8];
    float* out = (float*)d_out;
    (void)in_sizes; (void)n_in; (void)out_size; (void)ws_size;

    // Workspace carve (~64.4 MiB)
    uint8_t* w = (uint8_t*)d_ws;
    const size_t WMAT = (size_t)G4H * HH * 2;   // 8 MiB bf16 per matrix
    __hip_bfloat16* Wxs0 = (__hip_bfloat16*)(w);
    __hip_bfloat16* Whs0 = (__hip_bfloat16*)(w + WMAT);
    __hip_bfloat16* Wxs1 = (__hip_bfloat16*)(w + 2 * WMAT);
    __hip_bfloat16* Whs1 = (__hip_bfloat16*)(w + 3 * WMAT);
    size_t off = 4 * WMAT;
    __hip_bfloat16* xbuf = (__hip_bfloat16*)(w + off); off += (size_t)TT * BB * II * 2;
    __hip_bfloat16* h0buf = (__hip_bfloat16*)(w + off); off += 2 * (size_t)BH * 2;
    __hip_bfloat16* h1buf = (__hip_bfloat16*)(w + off); off += 2 * (size_t)BH * 2;
    unsigned* arr = (unsigned*)(w + off); off += 8192 * 4;

    init_bufs<<<(2 * BH) / 256, 256, 0, stream>>>(h0buf, h1buf, arr);
    shuffle_w<<<(G4H * HH) / 256, 256, 0, stream>>>(Wih0, Wxs0);
    shuffle_w<<<(G4H * HH) / 256, 256, 0, stream>>>(Whh0, Whs0);
    shuffle_w<<<(G4H * HH) / 256, 256, 0, stream>>>(Wih1, Wxs1);
    shuffle_w<<<(G4H * HH) / 256, 256, 0, stream>>>(Whh1, Whs1);
    convert_x<<<(TT * BB * II) / 256, 256, 0, stream>>>(x, xbuf);

    lstm_persist<<<256, 512, 0, stream>>>(xbuf, Wxs0, Whs0, Wxs1, Whs1,
                                          bih0, bhh0, bih1, bhh1,
                                          h0buf, h1buf, out, arr);
}